// Round 25
// baseline (19.932 us; speedup 1.0000x reference)
//
#include <hip/hip_runtime.h>
#include <math.h>

// B=4, X=128, T=256, HIDDEN=128, EMB=128, DH=32, LATENT=32, K=1024
// Outputs concat: u (131072), zt (1048576), px (524288)
// u[b,t,x] = K0 + sum_k zt[b,t,k]*px[b,x,k]*wc[k>>5]   (wc = wcd/32)
//
// R24 = R21 + bf16 side-band: feat writes bf16 copies of zt/px into ws;
// u stages bf16 directly (half the L3 bytes, no conversions in u) and applies
// wc per K=32 MFMA group in f32. Fallback to R21's u if ws too small.
// ws: [0..31] wc, [32] K0, [64..) zt_bf (1048576 shorts), px_bf (524288).

typedef __attribute__((ext_vector_type(8))) short short8v;   // 8 bf16
typedef __attribute__((ext_vector_type(4))) float f32x4;

struct P {
    const float *x, *t, *param;
    const float *p2e_W1, *p2e_b1, *p2e_W2, *p2e_b2;
    const float *e2ex_W, *e2ex_b, *e2et_W, *e2et_b;
    const float *px_Wx, *px_bx, *px_We, *px_be, *px_Wo, *px_bo, *px_mult;
    const float *zt_Wx, *zt_bx, *zt_We, *zt_be, *zt_Wo, *zt_bo, *zt_mult;
    const float *h0, *blk_W1, *blk_b1, *blk_Wc, *blk_bc, *blk_W2, *blk_b2;
    const float *d_W, *d_b;
    float *out_u, *out_zt, *out_px, *ws;
    unsigned short *ztbf_g, *pxbf_g;    // bf16 side-band (null if ws small)
};

__device__ __forceinline__ void fma4(float4& a, float s, const float4& v) {
    a.x += s * v.x; a.y += s * v.y; a.z += s * v.z; a.w += s * v.w;
}

__device__ __forceinline__ unsigned short f2bf(float f) {
    unsigned int u = __float_as_uint(f);
    return (unsigned short)((u + 0x7FFFu + ((u >> 16) & 1u)) >> 16);
}

// out[j] = bias[j] + sum_k vin[k] * W[k*128+j]; 256 threads. (R11 validated)
__device__ __forceinline__ void gemv_stage(
    const float* __restrict__ W, const float* __restrict__ bias,
    const float* vin, float* vout, float* partf, int tid)
{
    const int j4 = tid & 31;
    const int sl = tid >> 5;
    float4 a4 = make_float4(0.f, 0.f, 0.f, 0.f);
    const float* Wp = W + sl * 16 * 128 + j4 * 4;
    #pragma unroll
    for (int k = 0; k < 16; ++k)
        fma4(a4, vin[sl * 16 + k], *(const float4*)&Wp[k * 128]);
    *(float4*)&partf[sl * 128 + j4 * 4] = a4;
    __syncthreads();
    if (tid < 128) {
        float v = bias[tid];
        #pragma unroll
        for (int q = 0; q < 8; ++q) v += partf[q * 128 + tid];
        vout[tid] = v;
    }
    __syncthreads();
}

__global__ __launch_bounds__(256, 2) void feat_kernel(P p) {
    __shared__ float vin[128], vout[128];
    __shared__ float partf[1024];
    __shared__ unsigned short fbf[32 * 136];
    __shared__ unsigned short wot[128 * 136];
    const int tid = threadIdx.x;
    const int bid = blockIdx.x;

    if (bid < 384) {
        const bool is_zt = bid >= 128;
        int b, rt, cq;
        if (!is_zt) { b = bid >> 5;          rt = (bid >> 3) & 3;          cq = bid & 7; }
        else        { const int un = bid - 128; b = un >> 6; rt = (un >> 3) & 7; cq = un & 7; }
        const int R   = is_zt ? 256 : 128;
        const int r0g = b * R + rt * 32;
        const int co0 = cq * 128;

        const float* Wh = is_zt ? p.e2et_W : p.e2ex_W;
        const float* bh = is_zt ? p.e2et_b : p.e2ex_b;
        const float* We = is_zt ? p.zt_We : p.px_We;
        const float* be = is_zt ? p.zt_be : p.px_be;
        const float* Wx = is_zt ? p.zt_Wx : p.px_Wx;
        const float* bxv = is_zt ? p.zt_bx : p.px_bx;
        const float* Wo = is_zt ? p.zt_Wo : p.px_Wo;
        const float* bo = is_zt ? p.zt_bo : p.px_bo;
        const float* coord = is_zt ? p.t : p.x;
        const float mult = is_zt ? p.zt_mult[0] : p.px_mult[0];
        float* outp = is_zt ? p.out_zt : p.out_px;
        unsigned short* obf = is_zt ? p.ztbf_g : p.pxbf_g;

        // ---- g-chain (R11 validated) ----
        if (tid < 128) {
            float a = p.p2e_b1[tid];
            #pragma unroll
            for (int q = 0; q < 16; ++q)
                a += p.param[b * 16 + q] * p.p2e_W1[q * 128 + tid];
            vin[tid] = __sinf(a);
        }
        __syncthreads();
        gemv_stage(p.p2e_W2, p.p2e_b2, vin, vout, partf, tid);   // e
        gemv_stage(Wh, bh, vout, vin, partf, tid);               // ex/et
        gemv_stage(We, be, vin, vout, partf, tid);               // g in vout

        {
            const int j  = tid & 127;
            const int rh = tid >> 7;
            const float g = vout[j];
            const float wxj = Wx[j], bxj = bxv[j];
            #pragma unroll
            for (int rr = 0; rr < 16; ++rr) {
                const int row = rh * 16 + rr;
                fbf[row * 136 + j] =
                    f2bf(__sinf(coord[r0g + row] * wxj + bxj) * g);
            }
        }

        #pragma unroll
        for (int i = 0; i < 2; ++i) {
            const int s  = tid + 256 * i;
            const int kt = s >> 5;
            const int ct = s & 31;
            float4 r[8];
            #pragma unroll
            for (int kk = 0; kk < 8; ++kk)
                r[kk] = *(const float4*)&Wo[(kt * 8 + kk) * 1024 + co0 + ct * 4];
            #pragma unroll
            for (int c = 0; c < 4; ++c) {
                short8v o;
                #pragma unroll
                for (int kk = 0; kk < 8; ++kk)
                    o[kk] = (short)f2bf(((const float*)&r[kk])[c]);
                *(short8v*)&wot[(ct * 4 + c) * 136 + kt * 8] = o;
            }
        }
        __syncthreads();

        const int l   = tid & 63;
        const int wid = tid >> 6;
        f32x4 a00 = {0.f,0.f,0.f,0.f}, a01 = {0.f,0.f,0.f,0.f};
        f32x4 a10 = {0.f,0.f,0.f,0.f}, a11 = {0.f,0.f,0.f,0.f};
        const int rsel = (l & 15) * 136;
        #pragma unroll
        for (int ks = 0; ks < 4; ++ks) {
            const int koff = ks * 32 + (l >> 4) * 8;
            const short8v fa0 = *(const short8v*)&fbf[rsel + koff];
            const short8v fa1 = *(const short8v*)&fbf[16 * 136 + rsel + koff];
            const short8v wb0 = *(const short8v*)&wot[(wid * 32) * 136 + rsel + koff];
            const short8v wb1 = *(const short8v*)&wot[(wid * 32 + 16) * 136 + rsel + koff];
            a00 = __builtin_amdgcn_mfma_f32_16x16x32_bf16(fa0, wb0, a00, 0, 0, 0);
            a01 = __builtin_amdgcn_mfma_f32_16x16x32_bf16(fa0, wb1, a01, 0, 0, 0);
            a10 = __builtin_amdgcn_mfma_f32_16x16x32_bf16(fa1, wb0, a10, 0, 0, 0);
            a11 = __builtin_amdgcn_mfma_f32_16x16x32_bf16(fa1, wb1, a11, 0, 0, 0);
        }

        const int crow = (l >> 4) * 4;
        const int ccol = l & 15;
        const int cb   = co0 + wid * 32 + ccol;
        const float b0v = bo[cb];
        const float b1v = bo[cb + 16];
        #pragma unroll
        for (int r = 0; r < 4; ++r) {
            const int ra = (r0g + crow + r) * 1024;
            const int rb = (r0g + 16 + crow + r) * 1024;
            const float v00 = mult * (a00[r] + b0v);
            const float v01 = mult * (a01[r] + b1v);
            const float v10 = mult * (a10[r] + b0v);
            const float v11 = mult * (a11[r] + b1v);
            outp[ra + cb]      = v00;
            outp[ra + cb + 16] = v01;
            outp[rb + cb]      = v10;
            outp[rb + cb + 16] = v11;
            if (obf) {
                obf[ra + cb]      = f2bf(v00);
                obf[ra + cb + 16] = f2bf(v01);
                obf[rb + cb]      = f2bf(v10);
                obf[rb + cb + 16] = f2bf(v11);
            }
        }
    } else {
        // constants -> ws[0..31]=wc, ws[32]=K0 (R11 validated)
        __shared__ float dws[128];
        if (tid < 128) { vin[tid] = p.h0[tid]; dws[tid] = p.d_W[tid]; }
        __syncthreads();
        gemv_stage(p.blk_W1, p.blk_b1, vin, vout, partf, tid);   // sacc
        if (tid < 128) {
            float w2 = 0.f;
            const float4* rp = (const float4*)&p.blk_W2[tid * 128];
            #pragma unroll
            for (int m4 = 0; m4 < 32; ++m4) {
                const float4 wv = rp[m4];
                const float4 dv = *(const float4*)&dws[m4 * 4];
                w2 += wv.x * dv.x + wv.y * dv.y + wv.z * dv.z + wv.w * dv.w;
            }
            const float sv = __sinf(vout[tid]) * w2;
            vin[tid] = sv;
            vout[tid] = (p.h0[tid] + p.blk_b2[tid]) * dws[tid] + sv * p.blk_bc[tid];
        }
        __syncthreads();
        {
            const int d  = tid >> 3;
            const int sg = (tid & 7) * 16;
            float acc = 0.f;
            #pragma unroll
            for (int i4 = 0; i4 < 4; ++i4) {
                const float4 wv = *(const float4*)&p.blk_Wc[d * 128 + sg + i4 * 4];
                const float4 sv = *(const float4*)&vin[sg + i4 * 4];
                acc += wv.x * sv.x + wv.y * sv.y + wv.z * sv.z + wv.w * sv.w;
            }
            partf[d * 8 + (tid & 7)] = acc;
        }
        __syncthreads();
        if (tid < 32) {
            float w = 0.f;
            #pragma unroll
            for (int q = 0; q < 8; ++q) w += partf[tid * 8 + q];
            p.ws[tid] = w * (1.0f / 32.0f);
        }
        if (tid < 64) vout[tid] += vout[tid + 64];
        __syncthreads();
        if (tid == 0) {
            float K = p.d_b[0];
            #pragma unroll
            for (int i = 0; i < 64; ++i) K += vout[i];
            p.ws[32] = K;
        }
    }
}

// bf16-path u: 256 blocks = 4b x 16 t-tiles(16) x 4 x-quarters(32). 256 thr.
// Stages bf16 copies (half bytes, zero conversions); wc applied per K=32
// MFMA group in f32: acc += wc[d] * mfma(a, b, 0).
__global__ __launch_bounds__(256) void u_bf_kernel(
    const unsigned short* __restrict__ ztg, const unsigned short* __restrict__ pxg,
    const float* __restrict__ ws, float* __restrict__ out_u)
{
    __shared__ unsigned short ztbf[16 * 536];
    __shared__ unsigned short pxbf[32 * 536];
    __shared__ float red[4 * 2 * 256];
    __shared__ float wcs[32];
    __shared__ float K0s;

    const int tid = threadIdx.x;
    const int bid = blockIdx.x;
    const int b   = bid >> 6;
    const int rem = bid & 63;
    const int t0  = (rem >> 2) * 16;
    const int x0  = (rem & 3) * 32;

    if (tid < 32) wcs[tid] = ws[tid];
    if (tid == 32) K0s = ws[32];

    const unsigned short* ztb = ztg + (b * 256 + t0) * 1024;
    const unsigned short* pxb = pxg + (b * 128 + x0) * 1024;
    const int l   = tid & 63;
    const int wid = tid >> 6;

    f32x4 acc0 = {0.f, 0.f, 0.f, 0.f};
    f32x4 acc1 = {0.f, 0.f, 0.f, 0.f};

    __syncthreads();

    for (int h = 0; h < 2; ++h) {
        const int kb = h * 512;
        if (h) __syncthreads();

        // stage zt half: 16 rows x 512 shorts -> 1024 short8 (4/thread)
        #pragma unroll
        for (int i = 0; i < 4; ++i) {
            const int s   = tid + 256 * i;
            const int row = s >> 6;
            const int kc8 = (s & 63) * 8;
            *(short8v*)&ztbf[row * 536 + kc8] =
                *(const short8v*)&ztb[row * 1024 + kb + kc8];
        }
        // stage px half: 32 rows x 512 shorts (8/thread), unscaled
        #pragma unroll
        for (int i = 0; i < 8; ++i) {
            const int s   = tid + 256 * i;
            const int row = s >> 6;
            const int kc8 = (s & 63) * 8;
            *(short8v*)&pxbf[row * 536 + kc8] =
                *(const short8v*)&pxb[row * 1024 + kb + kc8];
        }
        __syncthreads();

        const int rsel = (l & 15) * 536;
        #pragma unroll
        for (int ks = 0; ks < 4; ++ks) {
            const int kloc = wid * 128 + ks * 32 + (l >> 4) * 8;
            const float w = wcs[h * 16 + wid * 4 + ks];
            const short8v a  = *(const short8v*)&ztbf[rsel + kloc];
            const short8v b0 = *(const short8v*)&pxbf[rsel + kloc];
            const short8v b1 = *(const short8v*)&pxbf[rsel + 16 * 536 + kloc];
            const f32x4 z = {0.f, 0.f, 0.f, 0.f};
            const f32x4 t0v = __builtin_amdgcn_mfma_f32_16x16x32_bf16(a, b0, z, 0, 0, 0);
            const f32x4 t1v = __builtin_amdgcn_mfma_f32_16x16x32_bf16(a, b1, z, 0, 0, 0);
            #pragma unroll
            for (int r = 0; r < 4; ++r) {
                acc0[r] += w * t0v[r];
                acc1[r] += w * t1v[r];
            }
        }
    }

    #pragma unroll
    for (int r = 0; r < 4; ++r) {
        red[(wid * 2 + 0) * 256 + l * 4 + r] = acc0[r];
        red[(wid * 2 + 1) * 256 + l * 4 + r] = acc1[r];
    }
    __syncthreads();

    {
        const int ll = tid & 63;
        const int rr = tid >> 6;
        const int ri = ll * 4 + rr;
        const int tt = t0 + ((ll >> 4) << 2) + rr;
        #pragma unroll
        for (int xt = 0; xt < 2; ++xt) {
            float sum = K0s;
            #pragma unroll
            for (int w = 0; w < 4; ++w) sum += red[(w * 2 + xt) * 256 + ri];
            const int xx = x0 + xt * 16 + (ll & 15);
            out_u[(b * 256 + tt) * 128 + xx] = sum;
        }
    }
}

// Fallback u (R21/R20 verbatim, f32 inputs): 256 blocks x 256 thr.
__global__ __launch_bounds__(256) void u_kernel(
    const float* __restrict__ zt, const float* __restrict__ px,
    const float* __restrict__ ws, float* __restrict__ out_u)
{
    __shared__ unsigned short ztbf[16 * 536];
    __shared__ unsigned short pxbf[32 * 536];
    __shared__ float red[4 * 2 * 256];
    __shared__ float wcs[32];
    __shared__ float K0s;

    const int tid = threadIdx.x;
    const int bid = blockIdx.x;
    const int b   = bid >> 6;
    const int rem = bid & 63;
    const int t0  = (rem >> 2) * 16;
    const int x0  = (rem & 3) * 32;

    if (tid < 32) wcs[tid] = ws[tid];
    if (tid == 32) K0s = ws[32];

    const float* ztb = zt + (b * 256 + t0) * 1024;
    const float* pxb = px + (b * 128 + x0) * 1024;
    const int l   = tid & 63;
    const int wid = tid >> 6;

    f32x4 acc0 = {0.f, 0.f, 0.f, 0.f};
    f32x4 acc1 = {0.f, 0.f, 0.f, 0.f};

    __syncthreads();

    for (int h = 0; h < 2; ++h) {
        const int kb = h * 512;
        if (h) __syncthreads();

        #pragma unroll
        for (int i = 0; i < 4; ++i) {
            const int s   = tid + 256 * i;
            const int row = s >> 6;
            const int kc8 = (s & 63) * 8;
            const float* src = ztb + row * 1024 + kb + kc8;
            const float4 v0 = *(const float4*)src;
            const float4 v1 = *(const float4*)(src + 4);
            short8v o;
            o[0] = (short)f2bf(v0.x); o[1] = (short)f2bf(v0.y);
            o[2] = (short)f2bf(v0.z); o[3] = (short)f2bf(v0.w);
            o[4] = (short)f2bf(v1.x); o[5] = (short)f2bf(v1.y);
            o[6] = (short)f2bf(v1.z); o[7] = (short)f2bf(v1.w);
            *(short8v*)&ztbf[row * 536 + kc8] = o;
        }
        #pragma unroll
        for (int i = 0; i < 8; ++i) {
            const int s   = tid + 256 * i;
            const int row = s >> 6;
            const int kc8 = (s & 63) * 8;
            const float sc = wcs[(kb + kc8) >> 5];
            const float* src = pxb + row * 1024 + kb + kc8;
            const float4 v0 = *(const float4*)src;
            const float4 v1 = *(const float4*)(src + 4);
            short8v o;
            o[0] = (short)f2bf(sc * v0.x); o[1] = (short)f2bf(sc * v0.y);
            o[2] = (short)f2bf(sc * v0.z); o[3] = (short)f2bf(sc * v0.w);
            o[4] = (short)f2bf(sc * v1.x); o[5] = (short)f2bf(sc * v1.y);
            o[6] = (short)f2bf(sc * v1.z); o[7] = (short)f2bf(sc * v1.w);
            *(short8v*)&pxbf[row * 536 + kc8] = o;
        }
        __syncthreads();

        const int rsel = (l & 15) * 536;
        #pragma unroll
        for (int ks = 0; ks < 4; ++ks) {
            const int kloc = wid * 128 + ks * 32 + (l >> 4) * 8;
            const short8v a  = *(const short8v*)&ztbf[rsel + kloc];
            const short8v b0 = *(const short8v*)&pxbf[rsel + kloc];
            const short8v b1 = *(const short8v*)&pxbf[rsel + 16 * 536 + kloc];
            acc0 = __builtin_amdgcn_mfma_f32_16x16x32_bf16(a, b0, acc0, 0, 0, 0);
            acc1 = __builtin_amdgcn_mfma_f32_16x16x32_bf16(a, b1, acc1, 0, 0, 0);
        }
    }

    #pragma unroll
    for (int r = 0; r < 4; ++r) {
        red[(wid * 2 + 0) * 256 + l * 4 + r] = acc0[r];
        red[(wid * 2 + 1) * 256 + l * 4 + r] = acc1[r];
    }
    __syncthreads();

    {
        const int ll = tid & 63;
        const int rr = tid >> 6;
        const int ri = ll * 4 + rr;
        const int tt = t0 + ((ll >> 4) << 2) + rr;
        #pragma unroll
        for (int xt = 0; xt < 2; ++xt) {
            float sum = K0s;
            #pragma unroll
            for (int w = 0; w < 4; ++w) sum += red[(w * 2 + xt) * 256 + ri];
            const int xx = x0 + xt * 16 + (ll & 15);
            out_u[(b * 256 + tt) * 128 + xx] = sum;
        }
    }
}

extern "C" void kernel_launch(void* const* d_in, const int* in_sizes, int n_in,
                              void* d_out, int out_size, void* d_ws, size_t ws_size,
                              hipStream_t stream) {
    float* out = (float*)d_out;
    float* ws  = (float*)d_ws;

    // bf16 side-band needs 64 floats header + 1.5M shorts = ~3.15 MB
    const size_t need = 64 * sizeof(float) + (size_t)(1048576 + 524288) * 2 + 4096;
    const bool use_bf = ws_size >= need;
    unsigned short* ztbf_g = use_bf ? (unsigned short*)(ws + 64) : nullptr;
    unsigned short* pxbf_g = use_bf ? (unsigned short*)(ws + 64) + 1048576 : nullptr;

    P prm;
    prm.x       = (const float*)d_in[0];
    prm.t       = (const float*)d_in[1];
    prm.param   = (const float*)d_in[2];
    prm.p2e_W1  = (const float*)d_in[3];
    prm.p2e_b1  = (const float*)d_in[4];
    prm.p2e_W2  = (const float*)d_in[5];
    prm.p2e_b2  = (const float*)d_in[6];
    prm.e2ex_W  = (const float*)d_in[7];
    prm.e2ex_b  = (const float*)d_in[8];
    prm.e2et_W  = (const float*)d_in[9];
    prm.e2et_b  = (const float*)d_in[10];
    prm.px_Wx   = (const float*)d_in[11];
    prm.px_bx   = (const float*)d_in[12];
    prm.px_We   = (const float*)d_in[13];
    prm.px_be   = (const float*)d_in[14];
    prm.px_Wo   = (const float*)d_in[15];
    prm.px_bo   = (const float*)d_in[16];
    prm.px_mult = (const float*)d_in[17];
    prm.zt_Wx   = (const float*)d_in[18];
    prm.zt_bx   = (const float*)d_in[19];
    prm.zt_We   = (const float*)d_in[20];
    prm.zt_be   = (const float*)d_in[21];
    prm.zt_Wo   = (const float*)d_in[22];
    prm.zt_bo   = (const float*)d_in[23];
    prm.zt_mult = (const float*)d_in[24];
    prm.h0      = (const float*)d_in[25];
    prm.blk_W1  = (const float*)d_in[26];
    prm.blk_b1  = (const float*)d_in[27];
    prm.blk_Wc  = (const float*)d_in[28];
    prm.blk_bc  = (const float*)d_in[29];
    prm.blk_W2  = (const float*)d_in[30];
    prm.blk_b2  = (const float*)d_in[31];
    prm.d_W     = (const float*)d_in[32];
    prm.d_b     = (const float*)d_in[33];
    prm.out_u   = out;                        // 131072
    prm.out_zt  = out + 131072;               // 1048576
    prm.out_px  = out + 131072 + 1048576;     // 524288
    prm.ws      = ws;
    prm.ztbf_g  = ztbf_g;
    prm.pxbf_g  = pxbf_g;

    feat_kernel<<<385, 256, 0, stream>>>(prm);
    if (use_bf)
        u_bf_kernel<<<256, 256, 0, stream>>>(ztbf_g, pxbf_g, ws, out);
    else
        u_kernel<<<256, 256, 0, stream>>>(prm.out_zt, prm.out_px, ws, out);
}